// Round 4
// baseline (307.120 us; speedup 1.0000x reference)
//
#include <hip/hip_runtime.h>
#include <hip/hip_bf16.h>

// Problem constants (fixed by setup_inputs)
#define B_    16
#define N1    1024
#define NP    4096
#define D1c   256
#define D2c   128
#define DH    256
#define NQ    (B_*NP)        // 65536 rows
#define KD1   (D1c+D2c)      // 384

// Workspace layout (bytes). Total 87,891,968.
#define X_OFF      0ul                     // x / x2 bf16: 65536*384*2
#define Y1_OFF     50331648ul              // y1 / y2 bf16: 65536*256*2
#define IDX_OFF    83886080ul              // int idx[65536*3]
#define W3_OFF     84672512ul              // float w[65536*3]
#define SCALE1_OFF 85458944ul
#define SHIFT1_OFF (SCALE1_OFF+1024ul)
#define SCALE2_OFF (SCALE1_OFF+2048ul)
#define SHIFT2_OFF (SCALE1_OFF+3072ul)
#define W1B_OFF    85467136ul              // bf16 W1: 256*384*2
#define W2B_OFF    85663744ul              // bf16 W2: 256*256*2
#define PS_OFF     85794816ul              // float Psum[256][1024] = 1 MB
#define PQ_OFF     86843392ul              // float Psq [256][1024] = 1 MB

using short8  = __attribute__((ext_vector_type(8))) short;
using floatx4 = __attribute__((ext_vector_type(4))) float;

// bf16 RNE cast (bit-level, matches np/jax round-to-nearest-even; inputs finite)
static __device__ __forceinline__ unsigned short f2b(float f) {
    unsigned int u = __builtin_bit_cast(unsigned int, f);
    return (unsigned short)((u + 0x7FFFu + ((u >> 16) & 1u)) >> 16);
}
static __device__ __forceinline__ float b2f(unsigned short u) {
    unsigned int x = ((unsigned int)u) << 16;
    return __builtin_bit_cast(float, x);
}

// ---------------- weights fp32 -> bf16 ----------------
__global__ __launch_bounds__(256) void cvt_weights(
    const float* __restrict__ W1, const float* __restrict__ W2,
    unsigned short* __restrict__ W1b, unsigned short* __restrict__ W2b)
{
    int i = blockIdx.x * 256 + threadIdx.x;          // 640 blocks -> 163840
    if (i < DH * KD1) W1b[i] = f2b(W1[i]);
    else              W2b[i - DH * KD1] = f2b(W2[i - DH * KD1]);
}

// ---------------- kNN (k=3), segmented for occupancy ----------------
// Block = 256 threads = 64 queries x 4 segments. Each thread scans 256
// candidates (wave-uniform LDS broadcast reads); partial top-3 lists merged
// in segment-ascending order with strict-< insertion, preserving the exact
// (dist asc, first-occurrence) semantics of the reference top_k.
// Distances in exact numpy fp32 order: ((dx*dx+dy*dy)+dz*dz), no fma.
__global__ __launch_bounds__(256) void knn_kernel(
    const float* __restrict__ xyz1, const float* __restrict__ xyz2,
    int* __restrict__ idx_out, float* __restrict__ w_out)
{
    __shared__ float sx[N1 * 3];      // 12 KB candidate points
    __shared__ float pd[12 * 64];     // partial dists  [(seg*3+k)*64 + ql]
    __shared__ int   pi[12 * 64];     // partial indices
    const int tid = threadIdx.x;
    const int batch = blockIdx.x >> 6;        // 16 batches x 64 blocks
    const int qblk  = blockIdx.x & 63;
    const float* src = xyz1 + (size_t)batch * (N1 * 3);
    for (int i = tid; i < (N1 * 3) / 4; i += 256)
        ((float4*)sx)[i] = ((const float4*)src)[i];
    __syncthreads();

    const int ql  = tid & 63;                 // query lane within block
    const int seg = tid >> 6;                 // candidate segment 0..3
    const int n = batch * NP + qblk * 64 + ql;
    const float* qp = xyz2 + (size_t)n * 3;
    const float qx = qp[0], qy = qp[1], qz = qp[2];

    float d0 = 3.4e38f, d1v = 3.4e38f, d2v = 3.4e38f;
    int   i0 = 0, i1 = 0, i2 = 0;

#define UPD(jj, cx, cy, cz) do {                                              \
        float dx = __fsub_rn(qx, (cx));                                       \
        float dy = __fsub_rn(qy, (cy));                                       \
        float dz = __fsub_rn(qz, (cz));                                       \
        float dd = __fadd_rn(__fadd_rn(__fmul_rn(dx,dx), __fmul_rn(dy,dy)),   \
                             __fmul_rn(dz,dz));                               \
        if (__any(dd < d2v)) {                                                \
            bool c2 = dd < d2v;                                               \
            d2v = c2 ? dd : d2v;  i2 = c2 ? (jj) : i2;                        \
            bool c1 = d2v < d1v;                                              \
            float tf = d1v; d1v = c1 ? d2v : d1v; d2v = c1 ? tf : d2v;        \
            int   ti = i1;  i1  = c1 ? i2  : i1;  i2  = c1 ? ti : i2;         \
            bool c0 = d1v < d0;                                               \
            tf = d0; d0 = c0 ? d1v : d0; d1v = c0 ? tf : d1v;                 \
            ti = i0; i0 = c0 ? i1  : i0; i1  = c0 ? ti : i1;                  \
        }                                                                     \
    } while (0)

    const int jbase = seg * 256;
    for (int j = 0; j < 256; j += 4) {
        const float* p = sx + (size_t)(jbase + j) * 3;
        float4 p0 = *(const float4*)(p);
        float4 p1 = *(const float4*)(p + 4);
        float4 p2 = *(const float4*)(p + 8);
        UPD(jbase + j + 0, p0.x, p0.y, p0.z);
        UPD(jbase + j + 1, p0.w, p1.x, p1.y);
        UPD(jbase + j + 2, p1.z, p1.w, p2.x);
        UPD(jbase + j + 3, p2.y, p2.z, p2.w);
    }
#undef UPD

    pd[(seg * 3 + 0) * 64 + ql] = d0;   pi[(seg * 3 + 0) * 64 + ql] = i0;
    pd[(seg * 3 + 1) * 64 + ql] = d1v;  pi[(seg * 3 + 1) * 64 + ql] = i1;
    pd[(seg * 3 + 2) * 64 + ql] = d2v;  pi[(seg * 3 + 2) * 64 + ql] = i2;
    __syncthreads();

    if (tid < 64) {
        // merge 12 entries in (segment asc, within-list asc) order
        float e0 = pd[0 * 64 + tid], e1 = pd[1 * 64 + tid], e2 = pd[2 * 64 + tid];
        int   j0 = pi[0 * 64 + tid], j1 = pi[1 * 64 + tid], j2 = pi[2 * 64 + tid];
#pragma unroll
        for (int s = 3; s < 12; s++) {
            float d = pd[s * 64 + tid];
            int   i = pi[s * 64 + tid];
            bool c2 = d < e2;
            e2 = c2 ? d : e2;  j2 = c2 ? i : j2;
            bool c1 = e2 < e1;
            float tf = e1; e1 = c1 ? e2 : e1; e2 = c1 ? tf : e2;
            int   ti = j1; j1 = c1 ? j2 : j1; j2 = c1 ? ti : j2;
            bool c0 = e1 < e0;
            tf = e0; e0 = c0 ? e1 : e0; e1 = c0 ? tf : e1;
            ti = j0; j0 = c0 ? j1 : j0; j1 = c0 ? ti : j1;
        }
        const int nq = batch * NP + qblk * 64 + tid;
        const float eps = 1.1920929e-07f;
        float v0 = 1.0f / __fadd_rn(e0, eps);
        float v1 = 1.0f / __fadd_rn(e1, eps);
        float v2 = 1.0f / __fadd_rn(e2, eps);
        float s  = __fadd_rn(__fadd_rn(v0, v1), v2);
        idx_out[nq * 3 + 0] = j0;  w_out[nq * 3 + 0] = v0 / s;
        idx_out[nq * 3 + 1] = j1;  w_out[nq * 3 + 1] = v1 / s;
        idx_out[nq * 3 + 2] = j2;  w_out[nq * 3 + 2] = v2 / s;
    }
}

// ---------------- interp + concat -> x bf16 ----------------
// One wave per query row; lane handles 4 interp channels + 2 f2 channels.
__global__ __launch_bounds__(256) void interp_kernel(
    const float* __restrict__ f1, const float* __restrict__ feat2,
    const int* __restrict__ idx3, const float* __restrict__ w3,
    unsigned short* __restrict__ x)
{
    int g = blockIdx.x * 256 + threadIdx.x;
    int wid = g >> 6;                 // query row 0..65535
    int lane = g & 63;
    int batch = wid >> 12;
    int i0 = idx3[wid * 3 + 0], i1 = idx3[wid * 3 + 1], i2 = idx3[wid * 3 + 2];
    float w0 = w3[wid * 3 + 0], w1 = w3[wid * 3 + 1], w2 = w3[wid * 3 + 2];
    const float* fb = f1 + (size_t)batch * N1 * D1c;
    float4 a = *(const float4*)(fb + (size_t)i0 * D1c + lane * 4);
    float4 b = *(const float4*)(fb + (size_t)i1 * D1c + lane * 4);
    float4 c = *(const float4*)(fb + (size_t)i2 * D1c + lane * 4);
    ushort4 o;
    o.x = f2b(__fadd_rn(__fadd_rn(__fmul_rn(a.x,w0), __fmul_rn(b.x,w1)), __fmul_rn(c.x,w2)));
    o.y = f2b(__fadd_rn(__fadd_rn(__fmul_rn(a.y,w0), __fmul_rn(b.y,w1)), __fmul_rn(c.y,w2)));
    o.z = f2b(__fadd_rn(__fadd_rn(__fmul_rn(a.z,w0), __fmul_rn(b.z,w1)), __fmul_rn(c.z,w2)));
    o.w = f2b(__fadd_rn(__fadd_rn(__fmul_rn(a.w,w0), __fmul_rn(b.w,w1)), __fmul_rn(c.w,w2)));
    *(ushort4*)(x + (size_t)wid * KD1 + lane * 4) = o;
    float2 f = *(const float2*)(feat2 + (size_t)wid * D2c + lane * 2);
    ushort2 o2; o2.x = f2b(f.x); o2.y = f2b(f.y);
    *(ushort2*)(x + (size_t)wid * KD1 + D1c + lane * 2) = o2;
}

// ---------------- GEMM (A: M x K, Bw: N x K "B^T"), bias + BN-partials fused ----
// LDS-free, barrier-free: A and B MFMA fragments loaded straight from global
// (16 B/lane, each 64-lane load = 16 dense 64 B lines; B is L2-resident).
// Register ping-pong 1-chunk-ahead prefetch -> fine-grained vmcnt, no vmcnt(0)
// drain (the m97-structure stall at tiny K). Output bf16; per-wave BN partials.
template<int KD>
__global__ __launch_bounds__(256) void gemm_bn(
    const unsigned short* __restrict__ A,
    const unsigned short* __restrict__ Bw,
    const float* __restrict__ bias,
    unsigned short* __restrict__ Out,
    float* __restrict__ Psum, float* __restrict__ Psq)
{
    const int tid  = threadIdx.x;
    const int wave = tid >> 6, lane = tid & 63;
    const int wm   = wave >> 1, wn = wave & 1;
    const int quad = lane >> 4, l16 = lane & 15;
    const long m0 = (long)blockIdx.x * 128;
    const int  n0 = blockIdx.y * 128;

    const unsigned short* Ap = A  + (size_t)(m0 + wm * 64 + l16) * KD + quad * 8;
    const unsigned short* Bp = Bw + (size_t)(n0 + wn * 64 + l16) * KD + quad * 8;

    floatx4 acc[4][4];
#pragma unroll
    for (int a = 0; a < 4; a++)
#pragma unroll
        for (int b = 0; b < 4; b++)
            acc[a][b] = floatx4{0.f, 0.f, 0.f, 0.f};

    constexpr int NK = KD / 32;
    short8 abuf[2][4], bbuf[2][4];
#pragma unroll
    for (int mb = 0; mb < 4; mb++)
        abuf[0][mb] = *(const short8*)(Ap + (size_t)mb * 16 * KD);
#pragma unroll
    for (int nb = 0; nb < 4; nb++)
        bbuf[0][nb] = *(const short8*)(Bp + (size_t)nb * 16 * KD);

#pragma unroll
    for (int ck = 0; ck < NK; ck++) {
        const int cur = ck & 1, nxt = cur ^ 1;
        if (ck + 1 < NK) {
#pragma unroll
            for (int mb = 0; mb < 4; mb++)
                abuf[nxt][mb] = *(const short8*)(Ap + (size_t)mb * 16 * KD + (ck + 1) * 32);
#pragma unroll
            for (int nb = 0; nb < 4; nb++)
                bbuf[nxt][nb] = *(const short8*)(Bp + (size_t)nb * 16 * KD + (ck + 1) * 32);
        }
#pragma unroll
        for (int mb = 0; mb < 4; mb++)
#pragma unroll
            for (int nb = 0; nb < 4; nb++)
                acc[mb][nb] = __builtin_amdgcn_mfma_f32_16x16x32_bf16(
                    abuf[cur][mb], bbuf[cur][nb], acc[mb][nb], 0, 0, 0);
    }

    // epilogue: +bias, bf16 store, per-column partial sum/sumsq (plain stores)
    const int pslot = blockIdx.x * 2 + wm;
#pragma unroll
    for (int nb = 0; nb < 4; nb++) {
        const int col = n0 + wn * 64 + nb * 16 + l16;
        const float bia = bias[col];
        float s = 0.f, q = 0.f;
#pragma unroll
        for (int mb = 0; mb < 4; mb++) {
            const size_t row = (size_t)(m0 + wm * 64 + mb * 16 + quad * 4);
#pragma unroll
            for (int r = 0; r < 4; r++) {
                float v = acc[mb][nb][r] + bia;
                s += v; q += v * v;
                Out[(row + r) * DH + col] = f2b(v);
            }
        }
        s += __shfl_xor(s, 16); s += __shfl_xor(s, 32);
        q += __shfl_xor(q, 16); q += __shfl_xor(q, 32);
        if (quad == 0) {
            Psum[col * 1024 + pslot] = s;
            Psq [col * 1024 + pslot] = q;
        }
    }
}

// ---------------- BN finalize: reduce 1024 partials/col -> scale/shift --------
__global__ __launch_bounds__(256) void finalize_bn(
    const float* __restrict__ Psum, const float* __restrict__ Psq,
    const float* __restrict__ g, const float* __restrict__ beta,
    float* __restrict__ scale, float* __restrict__ shift)
{
    __shared__ float ws_[4], wq_[4];
    const int c = blockIdx.x, t = threadIdx.x;
    float4 s4 = ((const float4*)(Psum + (size_t)c * 1024))[t];
    float4 q4 = ((const float4*)(Psq  + (size_t)c * 1024))[t];
    float s = (s4.x + s4.y) + (s4.z + s4.w);
    float q = (q4.x + q4.y) + (q4.z + q4.w);
#pragma unroll
    for (int o = 1; o < 64; o <<= 1) { s += __shfl_xor(s, o); q += __shfl_xor(q, o); }
    if ((t & 63) == 0) { ws_[t >> 6] = s; wq_[t >> 6] = q; }
    __syncthreads();
    if (t == 0) {
        s = (ws_[0] + ws_[1]) + (ws_[2] + ws_[3]);
        q = (wq_[0] + wq_[1]) + (wq_[2] + wq_[3]);
        float m  = s * (1.0f / (float)NQ);
        float v  = q * (1.0f / (float)NQ) - m * m;
        float rs = rsqrtf(v + 1e-5f);
        float a  = rs * g[c];
        scale[c] = a;
        shift[c] = fmaf(-m, a, beta[c]);
    }
}

// ---------------- BN apply + relu: y1 bf16 -> x2 bf16 ----------------
__global__ __launch_bounds__(256) void bn_apply(
    const unsigned short* __restrict__ y1, const float* __restrict__ scale,
    const float* __restrict__ shift, unsigned short* __restrict__ x2)
{
    size_t t = (size_t)blockIdx.x * 256 + threadIdx.x;   // 2,097,152 threads x 8 elems
    int c = ((int)t & 31) * 8;
    const ushort4* in = (const ushort4*)y1 + t * 2;
    ushort4 a = in[0], b = in[1];
    float4 s0 = *(const float4*)(scale + c), s1 = *(const float4*)(scale + c + 4);
    float4 h0 = *(const float4*)(shift + c), h1 = *(const float4*)(shift + c + 4);
    ushort4 oa, ob;
    oa.x = f2b(fmaxf(fmaf(b2f(a.x), s0.x, h0.x), 0.f));
    oa.y = f2b(fmaxf(fmaf(b2f(a.y), s0.y, h0.y), 0.f));
    oa.z = f2b(fmaxf(fmaf(b2f(a.z), s0.z, h0.z), 0.f));
    oa.w = f2b(fmaxf(fmaf(b2f(a.w), s0.w, h0.w), 0.f));
    ob.x = f2b(fmaxf(fmaf(b2f(b.x), s1.x, h1.x), 0.f));
    ob.y = f2b(fmaxf(fmaf(b2f(b.y), s1.y, h1.y), 0.f));
    ob.z = f2b(fmaxf(fmaf(b2f(b.z), s1.z, h1.z), 0.f));
    ob.w = f2b(fmaxf(fmaf(b2f(b.w), s1.w, h1.w), 0.f));
    ushort4* op = (ushort4*)x2 + t * 2;
    op[0] = oa; op[1] = ob;
}

// ---------------- final BN apply + relu: y2 bf16 -> d_out fp32 ----------------
__global__ __launch_bounds__(256) void final_apply(
    const unsigned short* __restrict__ y2, const float* __restrict__ scale,
    const float* __restrict__ shift, float* __restrict__ out)
{
    size_t t = (size_t)blockIdx.x * 256 + threadIdx.x;   // 2,097,152 threads x 8 elems
    int c = ((int)t & 31) * 8;
    const ushort4* in = (const ushort4*)y2 + t * 2;
    ushort4 a = in[0], b = in[1];
    float4 s0 = *(const float4*)(scale + c), s1 = *(const float4*)(scale + c + 4);
    float4 h0 = *(const float4*)(shift + c), h1 = *(const float4*)(shift + c + 4);
    float4 o0, o1;
    o0.x = fmaxf(fmaf(b2f(a.x), s0.x, h0.x), 0.f);
    o0.y = fmaxf(fmaf(b2f(a.y), s0.y, h0.y), 0.f);
    o0.z = fmaxf(fmaf(b2f(a.z), s0.z, h0.z), 0.f);
    o0.w = fmaxf(fmaf(b2f(a.w), s0.w, h0.w), 0.f);
    o1.x = fmaxf(fmaf(b2f(b.x), s1.x, h1.x), 0.f);
    o1.y = fmaxf(fmaf(b2f(b.y), s1.y, h1.y), 0.f);
    o1.z = fmaxf(fmaf(b2f(b.z), s1.z, h1.z), 0.f);
    o1.w = fmaxf(fmaf(b2f(b.w), s1.w, h1.w), 0.f);
    ((float4*)out)[t * 2]     = o0;
    ((float4*)out)[t * 2 + 1] = o1;
}

extern "C" void kernel_launch(void* const* d_in, const int* in_sizes, int n_in,
                              void* d_out, int out_size, void* d_ws, size_t ws_size,
                              hipStream_t stream) {
    (void)in_sizes; (void)n_in; (void)out_size; (void)ws_size;
    const float* xyz1 = (const float*)d_in[0];
    const float* xyz2 = (const float*)d_in[1];
    const float* f1   = (const float*)d_in[2];
    const float* f2   = (const float*)d_in[3];
    const float* W1   = (const float*)d_in[4];
    const float* b1   = (const float*)d_in[5];
    const float* g1   = (const float*)d_in[6];
    const float* be1  = (const float*)d_in[7];
    const float* W2   = (const float*)d_in[8];
    const float* b2   = (const float*)d_in[9];
    const float* g2   = (const float*)d_in[10];
    const float* be2  = (const float*)d_in[11];

    char* ws = (char*)d_ws;
    unsigned short* X    = (unsigned short*)(ws + X_OFF);     // x, later reused as x2
    unsigned short* Y1   = (unsigned short*)(ws + Y1_OFF);    // y1, later reused as y2
    int*            IDX  = (int*)(ws + IDX_OFF);
    float*          W3   = (float*)(ws + W3_OFF);
    float*          SC1  = (float*)(ws + SCALE1_OFF);
    float*          SH1  = (float*)(ws + SHIFT1_OFF);
    float*          SC2  = (float*)(ws + SCALE2_OFF);
    float*          SH2  = (float*)(ws + SHIFT2_OFF);
    unsigned short* W1b  = (unsigned short*)(ws + W1B_OFF);
    unsigned short* W2b  = (unsigned short*)(ws + W2B_OFF);
    float*          PS   = (float*)(ws + PS_OFF);
    float*          PQ   = (float*)(ws + PQ_OFF);

    cvt_weights<<<640, 256, 0, stream>>>(W1, W2, W1b, W2b);
    knn_kernel<<<1024, 256, 0, stream>>>(xyz1, xyz2, IDX, W3);
    interp_kernel<<<NQ / 4, 256, 0, stream>>>(f1, f2, IDX, W3, X);
    gemm_bn<KD1><<<dim3(NQ / 128, 2), 256, 0, stream>>>(X, W1b, b1, Y1, PS, PQ);
    finalize_bn<<<256, 256, 0, stream>>>(PS, PQ, g1, be1, SC1, SH1);
    bn_apply<<<(NQ * DH) / (8 * 256), 256, 0, stream>>>(Y1, SC1, SH1, X);
    gemm_bn<DH><<<dim3(NQ / 128, 2), 256, 0, stream>>>(X, W2b, b2, Y1, PS, PQ);
    finalize_bn<<<256, 256, 0, stream>>>(PS, PQ, g2, be2, SC2, SH2);
    final_apply<<<(NQ * DH) / (8 * 256), 256, 0, stream>>>(Y1, SC2, SH2, (float*)d_out);
}

// Round 5
// 268.639 us; speedup vs baseline: 1.1432x; 1.1432x over previous
//
#include <hip/hip_runtime.h>
#include <hip/hip_bf16.h>

// Problem constants (fixed by setup_inputs)
#define B_    16
#define N1    1024
#define NP    4096
#define D1c   256
#define D2c   128
#define DH    256
#define NQ    (B_*NP)        // 65536 rows
#define KD1   (D1c+D2c)      // 384

// Workspace layout (bytes).
#define X_OFF      0ul                     // x / x2 bf16: 65536*384*2
#define Y1_OFF     50331648ul              // y1 / y2 bf16: 65536*256*2
#define IDX_OFF    83886080ul              // int idx[65536*3]
#define W3_OFF     84672512ul              // float w[65536*3]
#define SCALE1_OFF 85458944ul
#define SHIFT1_OFF (SCALE1_OFF+1024ul)
#define SCALE2_OFF (SCALE1_OFF+2048ul)
#define SHIFT2_OFF (SCALE1_OFF+3072ul)
#define W1B_OFF    85467136ul              // bf16 W1: 256*384*2
#define W2B_OFF    85663744ul              // bf16 W2: 256*256*2
#define PS_OFF     85794816ul              // float Psum[1024][256] = 1 MB
#define PQ_OFF     86843392ul              // float Psq [1024][256] = 1 MB

using short8  = __attribute__((ext_vector_type(8))) short;
using floatx4 = __attribute__((ext_vector_type(4))) float;
typedef const __attribute__((address_space(1))) unsigned int* gas_t;
typedef __attribute__((address_space(3))) unsigned int* las_t;

// bf16 RNE cast (bit-level, matches np/jax round-to-nearest-even; inputs finite)
static __device__ __forceinline__ unsigned short f2b(float f) {
    unsigned int u = __builtin_bit_cast(unsigned int, f);
    return (unsigned short)((u + 0x7FFFu + ((u >> 16) & 1u)) >> 16);
}
static __device__ __forceinline__ float b2f(unsigned short u) {
    unsigned int x = ((unsigned int)u) << 16;
    return __builtin_bit_cast(float, x);
}

// ---------------- weights fp32 -> bf16 ----------------
__global__ __launch_bounds__(256) void cvt_weights(
    const float* __restrict__ W1, const float* __restrict__ W2,
    unsigned short* __restrict__ W1b, unsigned short* __restrict__ W2b)
{
    int i = blockIdx.x * 256 + threadIdx.x;          // 640 blocks -> 163840
    if (i < DH * KD1) W1b[i] = f2b(W1[i]);
    else              W2b[i - DH * KD1] = f2b(W2[i - DH * KD1]);
}

// ---------------- kNN (k=3), segmented for occupancy ----------------
__global__ __launch_bounds__(256) void knn_kernel(
    const float* __restrict__ xyz1, const float* __restrict__ xyz2,
    int* __restrict__ idx_out, float* __restrict__ w_out)
{
    __shared__ float sx[N1 * 3];      // 12 KB candidate points
    __shared__ float pd[12 * 64];     // partial dists  [(seg*3+k)*64 + ql]
    __shared__ int   pi[12 * 64];     // partial indices
    const int tid = threadIdx.x;
    const int batch = blockIdx.x >> 6;        // 16 batches x 64 blocks
    const int qblk  = blockIdx.x & 63;
    const float* src = xyz1 + (size_t)batch * (N1 * 3);
    for (int i = tid; i < (N1 * 3) / 4; i += 256)
        ((float4*)sx)[i] = ((const float4*)src)[i];
    __syncthreads();

    const int ql  = tid & 63;                 // query lane within block
    const int seg = tid >> 6;                 // candidate segment 0..3
    const int n = batch * NP + qblk * 64 + ql;
    const float* qp = xyz2 + (size_t)n * 3;
    const float qx = qp[0], qy = qp[1], qz = qp[2];

    float d0 = 3.4e38f, d1v = 3.4e38f, d2v = 3.4e38f;
    int   i0 = 0, i1 = 0, i2 = 0;

#define UPD(jj, cx, cy, cz) do {                                              \
        float dx = __fsub_rn(qx, (cx));                                       \
        float dy = __fsub_rn(qy, (cy));                                       \
        float dz = __fsub_rn(qz, (cz));                                       \
        float dd = __fadd_rn(__fadd_rn(__fmul_rn(dx,dx), __fmul_rn(dy,dy)),   \
                             __fmul_rn(dz,dz));                               \
        if (__any(dd < d2v)) {                                                \
            bool c2 = dd < d2v;                                               \
            d2v = c2 ? dd : d2v;  i2 = c2 ? (jj) : i2;                        \
            bool c1 = d2v < d1v;                                              \
            float tf = d1v; d1v = c1 ? d2v : d1v; d2v = c1 ? tf : d2v;        \
            int   ti = i1;  i1  = c1 ? i2  : i1;  i2  = c1 ? ti : i2;         \
            bool c0 = d1v < d0;                                               \
            tf = d0; d0 = c0 ? d1v : d0; d1v = c0 ? tf : d1v;                 \
            ti = i0; i0 = c0 ? i1  : i0; i1  = c0 ? ti : i1;                  \
        }                                                                     \
    } while (0)

    const int jbase = seg * 256;
    for (int j = 0; j < 256; j += 4) {
        const float* p = sx + (size_t)(jbase + j) * 3;
        float4 p0 = *(const float4*)(p);
        float4 p1 = *(const float4*)(p + 4);
        float4 p2 = *(const float4*)(p + 8);
        UPD(jbase + j + 0, p0.x, p0.y, p0.z);
        UPD(jbase + j + 1, p0.w, p1.x, p1.y);
        UPD(jbase + j + 2, p1.z, p1.w, p2.x);
        UPD(jbase + j + 3, p2.y, p2.z, p2.w);
    }
#undef UPD

    pd[(seg * 3 + 0) * 64 + ql] = d0;   pi[(seg * 3 + 0) * 64 + ql] = i0;
    pd[(seg * 3 + 1) * 64 + ql] = d1v;  pi[(seg * 3 + 1) * 64 + ql] = i1;
    pd[(seg * 3 + 2) * 64 + ql] = d2v;  pi[(seg * 3 + 2) * 64 + ql] = i2;
    __syncthreads();

    if (tid < 64) {
        // merge 12 entries in (segment asc, within-list asc) order
        float e0 = pd[0 * 64 + tid], e1 = pd[1 * 64 + tid], e2 = pd[2 * 64 + tid];
        int   j0 = pi[0 * 64 + tid], j1 = pi[1 * 64 + tid], j2 = pi[2 * 64 + tid];
#pragma unroll
        for (int s = 3; s < 12; s++) {
            float d = pd[s * 64 + tid];
            int   i = pi[s * 64 + tid];
            bool c2 = d < e2;
            e2 = c2 ? d : e2;  j2 = c2 ? i : j2;
            bool c1 = e2 < e1;
            float tf = e1; e1 = c1 ? e2 : e1; e2 = c1 ? tf : e2;
            int   ti = j1; j1 = c1 ? j2 : j1; j2 = c1 ? ti : j2;
            bool c0 = e1 < e0;
            tf = e0; e0 = c0 ? e1 : e0; e1 = c0 ? tf : e1;
            ti = j0; j0 = c0 ? j1 : j0; j1 = c0 ? ti : j1;
        }
        const int nq = batch * NP + qblk * 64 + tid;
        const float eps = 1.1920929e-07f;
        float v0 = 1.0f / __fadd_rn(e0, eps);
        float v1 = 1.0f / __fadd_rn(e1, eps);
        float v2 = 1.0f / __fadd_rn(e2, eps);
        float s  = __fadd_rn(__fadd_rn(v0, v1), v2);
        idx_out[nq * 3 + 0] = j0;  w_out[nq * 3 + 0] = v0 / s;
        idx_out[nq * 3 + 1] = j1;  w_out[nq * 3 + 1] = v1 / s;
        idx_out[nq * 3 + 2] = j2;  w_out[nq * 3 + 2] = v2 / s;
    }
}

// ---------------- interp + concat -> x bf16 ----------------
__global__ __launch_bounds__(256) void interp_kernel(
    const float* __restrict__ f1, const float* __restrict__ feat2,
    const int* __restrict__ idx3, const float* __restrict__ w3,
    unsigned short* __restrict__ x)
{
    int g = blockIdx.x * 256 + threadIdx.x;
    int wid = g >> 6;                 // query row 0..65535
    int lane = g & 63;
    int batch = wid >> 12;
    int i0 = idx3[wid * 3 + 0], i1 = idx3[wid * 3 + 1], i2 = idx3[wid * 3 + 2];
    float w0 = w3[wid * 3 + 0], w1 = w3[wid * 3 + 1], w2 = w3[wid * 3 + 2];
    const float* fb = f1 + (size_t)batch * N1 * D1c;
    float4 a = *(const float4*)(fb + (size_t)i0 * D1c + lane * 4);
    float4 b = *(const float4*)(fb + (size_t)i1 * D1c + lane * 4);
    float4 c = *(const float4*)(fb + (size_t)i2 * D1c + lane * 4);
    ushort4 o;
    o.x = f2b(__fadd_rn(__fadd_rn(__fmul_rn(a.x,w0), __fmul_rn(b.x,w1)), __fmul_rn(c.x,w2)));
    o.y = f2b(__fadd_rn(__fadd_rn(__fmul_rn(a.y,w0), __fmul_rn(b.y,w1)), __fmul_rn(c.y,w2)));
    o.z = f2b(__fadd_rn(__fadd_rn(__fmul_rn(a.z,w0), __fmul_rn(b.z,w1)), __fmul_rn(c.z,w2)));
    o.w = f2b(__fadd_rn(__fadd_rn(__fmul_rn(a.w,w0), __fmul_rn(b.w,w1)), __fmul_rn(c.w,w2)));
    *(ushort4*)(x + (size_t)wid * KD1 + lane * 4) = o;
    float2 f = *(const float2*)(feat2 + (size_t)wid * D2c + lane * 2);
    ushort2 o2; o2.x = f2b(f.x); o2.y = f2b(f.y);
    *(ushort2*)(x + (size_t)wid * KD1 + D1c + lane * 2) = o2;
}

// ---------------- GEMM (A: M x K, Bw: 256 x K "B^T"), bias + BN-partials fused --
// 512 threads = 8 waves (2 m-halves x 4 n-quarters of 64x64). Full N=256 per
// block -> A read once. Single-barrier double-buffer: stage(ck+1) -> compute(ck)
// -> __syncthreads(); the barrier's vmcnt(0) drain waits loads that have been in
// flight for the whole compute phase. Epilogue: LDS transpose -> contiguous
// 16 B/lane stores (no partial-sector RMW). BN partials: P[slot][col], 64 B rows.
template<int KD>
__global__ __launch_bounds__(512, 2) void gemm_bn(
    const unsigned short* __restrict__ A,
    const unsigned short* __restrict__ Bw,
    const float* __restrict__ bias,
    unsigned short* __restrict__ Out,
    float* __restrict__ Psum, float* __restrict__ Psq)
{
    __shared__ short smem[24576];   // 48 KB: As[2] @ 0/4096, Bs[2] @ 8192/16384
    const int tid  = threadIdx.x;
    const int wave = tid >> 6, lane = tid & 63;
    const int wm   = wave & 1, wn = wave >> 1;
    const int quad = lane >> 4, l16 = lane & 15;
    const long m0 = (long)blockIdx.x * 128;

    // staging: thread tid covers row tid>>2 (A: 128 rows, B: 2x128 rows),
    // global K-chunk cg = (tid&3) ^ ((tid>>3)&3)  (bank swizzle, R2-verified)
    const int srow = tid >> 2;
    const int cg   = ((tid & 3) ^ ((tid >> 3) & 3)) * 8;
    const size_t aoff  = (size_t)(m0 + srow) * KD + cg;
    const size_t boff0 = (size_t)(srow) * KD + cg;
    const size_t boff1 = (size_t)(128 + srow) * KD + cg;

    floatx4 acc[4][4];
#pragma unroll
    for (int a = 0; a < 4; a++)
#pragma unroll
        for (int b = 0; b < 4; b++)
            acc[a][b] = floatx4{0.f, 0.f, 0.f, 0.f};

    const int rsw = (l16 >> 1) & 3;   // fragment-read swizzle
    constexpr int NK = KD / 32;

#define STAGE(buf, ck) do {                                                         \
        __builtin_amdgcn_global_load_lds((gas_t)(const void*)(A + aoff + (ck)*32),  \
            (las_t)(void*)(smem + (buf)*4096 + wave*512), 16, 0, 0);                \
        __builtin_amdgcn_global_load_lds((gas_t)(const void*)(Bw + boff0 + (ck)*32),\
            (las_t)(void*)(smem + 8192 + (buf)*8192 + wave*512), 16, 0, 0);         \
        __builtin_amdgcn_global_load_lds((gas_t)(const void*)(Bw + boff1 + (ck)*32),\
            (las_t)(void*)(smem + 8192 + (buf)*8192 + 4096 + wave*512), 16, 0, 0);  \
    } while (0)

    STAGE(0, 0);
    __syncthreads();

    for (int ck = 0; ck < NK; ck++) {
        const int cur = ck & 1;
        if (ck + 1 < NK) STAGE(cur ^ 1, ck + 1);

        const short* Ab = smem + cur * 4096;
        const short* Bb = smem + 8192 + cur * 8192;
        short8 af[4], bfr[4];
#pragma unroll
        for (int mb = 0; mb < 4; mb++)
            af[mb] = *(const short8*)(Ab + (wm * 64 + mb * 16 + l16) * 32 + ((quad ^ rsw) * 8));
#pragma unroll
        for (int nb = 0; nb < 4; nb++)
            bfr[nb] = *(const short8*)(Bb + (wn * 64 + nb * 16 + l16) * 32 + ((quad ^ rsw) * 8));
#pragma unroll
        for (int mb = 0; mb < 4; mb++)
#pragma unroll
            for (int nb = 0; nb < 4; nb++)
                acc[mb][nb] = __builtin_amdgcn_mfma_f32_16x16x32_bf16(af[mb], bfr[nb], acc[mb][nb], 0, 0, 0);
        __syncthreads();
    }
#undef STAGE

    // bias + BN partials (P[slot][col]: contiguous 64 B per 16-lane store)
    const int pslot = blockIdx.x * 2 + wm;
#pragma unroll
    for (int nb = 0; nb < 4; nb++) {
        const int col = wn * 64 + nb * 16 + l16;
        const float bia = bias[col];
        float s = 0.f, q = 0.f;
#pragma unroll
        for (int mb = 0; mb < 4; mb++)
#pragma unroll
            for (int r = 0; r < 4; r++) {
                float v = acc[mb][nb][r] + bia;
                acc[mb][nb][r] = v;
                s += v; q += v * v;
            }
        s += __shfl_xor(s, 16); s += __shfl_xor(s, 32);
        q += __shfl_xor(q, 16); q += __shfl_xor(q, 32);
        if (quad == 0) {
            Psum[pslot * 256 + col] = s;
            Psq [pslot * 256 + col] = q;
        }
    }

    // epilogue: 2 passes of 64 rows through LDS (32 KB), contiguous stores.
    // LDS slot for (row_local rl, col j): rl*256 + ((j>>3)+rl & 31)*8 + (j&7)
#pragma unroll
    for (int p = 0; p < 2; p++) {
        __syncthreads();
        if (wm == p) {
#pragma unroll
            for (int mb = 0; mb < 4; mb++)
#pragma unroll
                for (int r = 0; r < 4; r++) {
                    const int rl = mb * 16 + quad * 4 + r;
#pragma unroll
                    for (int nb = 0; nb < 4; nb++) {
                        const int col = wn * 64 + nb * 16 + l16;
                        smem[rl * 256 + ((((col >> 3) + rl) & 31) << 3) + (col & 7)] =
                            (short)f2b(acc[mb][nb][r]);
                    }
                }
        }
        __syncthreads();
#pragma unroll
        for (int rr = 0; rr < 4; rr++) {
            const int rl = rr * 16 + (tid >> 5);
            const int c  = tid & 31;
            short8 v = *(const short8*)(smem + rl * 256 + (((c + rl) & 31) << 3));
            *(short8*)(Out + (size_t)(m0 + p * 64 + rl) * 256 + c * 8) = v;
        }
    }
}

// ---------------- BN finalize: reduce P[1024][256] -> scale/shift --------
// 8 blocks x 256 thr: block covers 32 cols; tid>>5 = slot-group (128 slots each)
__global__ __launch_bounds__(256) void finalize_bn(
    const float* __restrict__ Psum, const float* __restrict__ Psq,
    const float* __restrict__ g, const float* __restrict__ beta,
    float* __restrict__ scale, float* __restrict__ shift)
{
    __shared__ float ls[8][32], lq[8][32];
    const int cl = threadIdx.x & 31, grp = threadIdx.x >> 5;
    const int c = blockIdx.x * 32 + cl;
    float s = 0.f, q = 0.f;
    for (int k = grp * 128; k < grp * 128 + 128; k++) {
        s += Psum[k * 256 + c];
        q += Psq [k * 256 + c];
    }
    ls[grp][cl] = s; lq[grp][cl] = q;
    __syncthreads();
    if (grp == 0) {
#pragma unroll
        for (int k = 1; k < 8; k++) { s += ls[k][cl]; q += lq[k][cl]; }
        float m  = s * (1.0f / (float)NQ);
        float v  = q * (1.0f / (float)NQ) - m * m;
        float rs = rsqrtf(v + 1e-5f);
        float a  = rs * g[c];
        scale[c] = a;
        shift[c] = fmaf(-m, a, beta[c]);
    }
}

// ---------------- BN apply + relu: y1 bf16 -> x2 bf16 ----------------
__global__ __launch_bounds__(256) void bn_apply(
    const unsigned short* __restrict__ y1, const float* __restrict__ scale,
    const float* __restrict__ shift, unsigned short* __restrict__ x2)
{
    size_t t = (size_t)blockIdx.x * 256 + threadIdx.x;   // 2,097,152 threads x 8 elems
    int c = ((int)t & 31) * 8;
    const ushort4* in = (const ushort4*)y1 + t * 2;
    ushort4 a = in[0], b = in[1];
    float4 s0 = *(const float4*)(scale + c), s1 = *(const float4*)(scale + c + 4);
    float4 h0 = *(const float4*)(shift + c), h1 = *(const float4*)(shift + c + 4);
    ushort4 oa, ob;
    oa.x = f2b(fmaxf(fmaf(b2f(a.x), s0.x, h0.x), 0.f));
    oa.y = f2b(fmaxf(fmaf(b2f(a.y), s0.y, h0.y), 0.f));
    oa.z = f2b(fmaxf(fmaf(b2f(a.z), s0.z, h0.z), 0.f));
    oa.w = f2b(fmaxf(fmaf(b2f(a.w), s0.w, h0.w), 0.f));
    ob.x = f2b(fmaxf(fmaf(b2f(b.x), s1.x, h1.x), 0.f));
    ob.y = f2b(fmaxf(fmaf(b2f(b.y), s1.y, h1.y), 0.f));
    ob.z = f2b(fmaxf(fmaf(b2f(b.z), s1.z, h1.z), 0.f));
    ob.w = f2b(fmaxf(fmaf(b2f(b.w), s1.w, h1.w), 0.f));
    ushort4* op = (ushort4*)x2 + t * 2;
    op[0] = oa; op[1] = ob;
}

// ---------------- final BN apply + relu: y2 bf16 -> d_out fp32 ----------------
__global__ __launch_bounds__(256) void final_apply(
    const unsigned short* __restrict__ y2, const float* __restrict__ scale,
    const float* __restrict__ shift, float* __restrict__ out)
{
    size_t t = (size_t)blockIdx.x * 256 + threadIdx.x;   // 2,097,152 threads x 8 elems
    int c = ((int)t & 31) * 8;
    const ushort4* in = (const ushort4*)y2 + t * 2;
    ushort4 a = in[0], b = in[1];
    float4 s0 = *(const float4*)(scale + c), s1 = *(const float4*)(scale + c + 4);
    float4 h0 = *(const float4*)(shift + c), h1 = *(const float4*)(shift + c + 4);
    float4 o0, o1;
    o0.x = fmaxf(fmaf(b2f(a.x), s0.x, h0.x), 0.f);
    o0.y = fmaxf(fmaf(b2f(a.y), s0.y, h0.y), 0.f);
    o0.z = fmaxf(fmaf(b2f(a.z), s0.z, h0.z), 0.f);
    o0.w = fmaxf(fmaf(b2f(a.w), s0.w, h0.w), 0.f);
    o1.x = fmaxf(fmaf(b2f(b.x), s1.x, h1.x), 0.f);
    o1.y = fmaxf(fmaf(b2f(b.y), s1.y, h1.y), 0.f);
    o1.z = fmaxf(fmaf(b2f(b.z), s1.z, h1.z), 0.f);
    o1.w = fmaxf(fmaf(b2f(b.w), s1.w, h1.w), 0.f);
    ((float4*)out)[t * 2]     = o0;
    ((float4*)out)[t * 2 + 1] = o1;
}

extern "C" void kernel_launch(void* const* d_in, const int* in_sizes, int n_in,
                              void* d_out, int out_size, void* d_ws, size_t ws_size,
                              hipStream_t stream) {
    (void)in_sizes; (void)n_in; (void)out_size; (void)ws_size;
    const float* xyz1 = (const float*)d_in[0];
    const float* xyz2 = (const float*)d_in[1];
    const float* f1   = (const float*)d_in[2];
    const float* f2   = (const float*)d_in[3];
    const float* W1   = (const float*)d_in[4];
    const float* b1   = (const float*)d_in[5];
    const float* g1   = (const float*)d_in[6];
    const float* be1  = (const float*)d_in[7];
    const float* W2   = (const float*)d_in[8];
    const float* b2   = (const float*)d_in[9];
    const float* g2   = (const float*)d_in[10];
    const float* be2  = (const float*)d_in[11];

    char* ws = (char*)d_ws;
    unsigned short* X    = (unsigned short*)(ws + X_OFF);     // x, later reused as x2
    unsigned short* Y1   = (unsigned short*)(ws + Y1_OFF);    // y1, later reused as y2
    int*            IDX  = (int*)(ws + IDX_OFF);
    float*          W3   = (float*)(ws + W3_OFF);
    float*          SC1  = (float*)(ws + SCALE1_OFF);
    float*          SH1  = (float*)(ws + SHIFT1_OFF);
    float*          SC2  = (float*)(ws + SCALE2_OFF);
    float*          SH2  = (float*)(ws + SHIFT2_OFF);
    unsigned short* W1b  = (unsigned short*)(ws + W1B_OFF);
    unsigned short* W2b  = (unsigned short*)(ws + W2B_OFF);
    float*          PS   = (float*)(ws + PS_OFF);
    float*          PQ   = (float*)(ws + PQ_OFF);

    cvt_weights<<<640, 256, 0, stream>>>(W1, W2, W1b, W2b);
    knn_kernel<<<1024, 256, 0, stream>>>(xyz1, xyz2, IDX, W3);
    interp_kernel<<<NQ / 4, 256, 0, stream>>>(f1, f2, IDX, W3, X);
    gemm_bn<KD1><<<512, 512, 0, stream>>>(X, W1b, b1, Y1, PS, PQ);
    finalize_bn<<<8, 256, 0, stream>>>(PS, PQ, g1, be1, SC1, SH1);
    bn_apply<<<(NQ * DH) / (8 * 256), 256, 0, stream>>>(Y1, SC1, SH1, X);
    gemm_bn<DH><<<512, 512, 0, stream>>>(X, W2b, b2, Y1, PS, PQ);
    finalize_bn<<<8, 256, 0, stream>>>(PS, PQ, g2, be2, SC2, SH2);
    final_apply<<<(NQ * DH) / (8 * 256), 256, 0, stream>>>(Y1, SC2, SH2, (float*)d_out);
}

// Round 6
// 261.906 us; speedup vs baseline: 1.1726x; 1.0257x over previous
//
#include <hip/hip_runtime.h>
#include <hip/hip_bf16.h>

// Problem constants (fixed by setup_inputs)
#define B_    16
#define N1    1024
#define NP    4096
#define D1c   256
#define D2c   128
#define DH    256
#define NQ    (B_*NP)        // 65536 rows
#define KD1   (D1c+D2c)      // 384

// Workspace layout (bytes).
#define X_OFF      0ul                     // x / x2 bf16: 65536*384*2
#define Y1_OFF     50331648ul              // y1 / y2 bf16: 65536*256*2
#define SCALE1_OFF 85458944ul
#define SHIFT1_OFF (SCALE1_OFF+1024ul)
#define SCALE2_OFF (SCALE1_OFF+2048ul)
#define SHIFT2_OFF (SCALE1_OFF+3072ul)
#define W1B_OFF    85467136ul              // bf16 W1: 256*384*2
#define W2B_OFF    85663744ul              // bf16 W2: 256*256*2
#define PS_OFF     85794816ul              // float Psum[1024][256] = 1 MB
#define PQ_OFF     86843392ul              // float Psq [1024][256] = 1 MB

using short8  = __attribute__((ext_vector_type(8))) short;
using floatx4 = __attribute__((ext_vector_type(4))) float;
using f4v     = __attribute__((ext_vector_type(4))) float;
typedef const __attribute__((address_space(1))) unsigned int* gas_t;
typedef __attribute__((address_space(3))) unsigned int* las_t;
typedef const __attribute__((address_space(4))) float* c4f_t;   // constant AS -> s_load
typedef const __attribute__((address_space(4))) f4v*   c4v_t;

// bf16 RNE cast (bit-level, matches np/jax round-to-nearest-even; inputs finite)
static __device__ __forceinline__ unsigned short f2b(float f) {
    unsigned int u = __builtin_bit_cast(unsigned int, f);
    return (unsigned short)((u + 0x7FFFu + ((u >> 16) & 1u)) >> 16);
}
static __device__ __forceinline__ float b2f(unsigned short u) {
    unsigned int x = ((unsigned int)u) << 16;
    return __builtin_bit_cast(float, x);
}

// ---------------- fused kNN + interp/concat (+ weight cvt on spare blocks) ----
// Blocks 0..1023: 64 queries each. Phase 1: kNN k=3 (4 segments x 256 cands per
// thread; candidate loads via constant-AS scalar loads -- wave-uniform segment,
// readfirstlane-forced -> s_load, freeing VALU+LDS pipes). Phase 2: merge
// partial top-3 lists (exact (dist asc, first-occurrence) top_k semantics;
// distances bit-exact numpy fp32 order: ((dx*dx+dy*dy)+dz*dz), no fma).
// Phase 3: same block interpolates + concats its 64 rows into x (bf16).
// Blocks 1024..1663: W1/W2 fp32->bf16 conversion.
__global__ __launch_bounds__(256) void knn_interp_kernel(
    const float* __restrict__ xyz1, const float* __restrict__ xyz2,
    const float* __restrict__ f1,   const float* __restrict__ feat2,
    const float* __restrict__ W1,   const float* __restrict__ W2,
    unsigned short* __restrict__ W1b, unsigned short* __restrict__ W2b,
    unsigned short* __restrict__ x)
{
    const int tid = threadIdx.x;
    if (blockIdx.x >= 1024) {            // ---- weight conversion blocks ----
        int i = (blockIdx.x - 1024) * 256 + tid;
        if (i < DH * KD1) W1b[i] = f2b(W1[i]);
        else              W2b[i - DH * KD1] = f2b(W2[i - DH * KD1]);
        return;
    }

    __shared__ float pd[12 * 64];     // partial dists  [(seg*3+k)*64 + ql]
    __shared__ int   pi[12 * 64];     // partial indices
    __shared__ int   sidx[64 * 3];
    __shared__ float swt [64 * 3];

    const int batch = blockIdx.x >> 6;        // 16 batches x 64 blocks
    const int qblk  = blockIdx.x & 63;
    const int ql  = tid & 63;                 // query lane within block
    const int seg = tid >> 6;                 // candidate segment 0..3
    const int seg_u = __builtin_amdgcn_readfirstlane(seg);   // wave-uniform
    const int n = batch * NP + qblk * 64 + ql;
    const float* qp = xyz2 + (size_t)n * 3;
    const float qx = qp[0], qy = qp[1], qz = qp[2];

    // candidate pointer: constant-AS, uniform -> scalar loads (48 B / 4 cands)
    c4f_t cp = (c4f_t)(const void*)(xyz1 + (size_t)batch * (N1 * 3))
               + (size_t)seg_u * 768;

    float d0 = 3.4e38f, d1v = 3.4e38f, d2v = 3.4e38f;
    int   i0 = 0, i1 = 0, i2 = 0;

#define UPD(jj, cx, cy, cz) do {                                              \
        float dx = __fsub_rn(qx, (cx));                                       \
        float dy = __fsub_rn(qy, (cy));                                       \
        float dz = __fsub_rn(qz, (cz));                                       \
        float dd = __fadd_rn(__fadd_rn(__fmul_rn(dx,dx), __fmul_rn(dy,dy)),   \
                             __fmul_rn(dz,dz));                               \
        if (__any(dd < d2v)) {                                                \
            bool c2 = dd < d2v;                                               \
            d2v = c2 ? dd : d2v;  i2 = c2 ? (jj) : i2;                        \
            bool c1 = d2v < d1v;                                              \
            float tf = d1v; d1v = c1 ? d2v : d1v; d2v = c1 ? tf : d2v;        \
            int   ti = i1;  i1  = c1 ? i2  : i1;  i2  = c1 ? ti : i2;         \
            bool c0 = d1v < d0;                                               \
            tf = d0; d0 = c0 ? d1v : d0; d1v = c0 ? tf : d1v;                 \
            ti = i0; i0 = c0 ? i1  : i0; i1  = c0 ? ti : i1;                  \
        }                                                                     \
    } while (0)

    const int jbase = seg_u * 256;
    for (int j = 0; j < 256; j += 4) {
        f4v p0 = *(c4v_t)(cp + j * 3);
        f4v p1 = *(c4v_t)(cp + j * 3 + 4);
        f4v p2 = *(c4v_t)(cp + j * 3 + 8);
        UPD(jbase + j + 0, p0.x, p0.y, p0.z);
        UPD(jbase + j + 1, p0.w, p1.x, p1.y);
        UPD(jbase + j + 2, p1.z, p1.w, p2.x);
        UPD(jbase + j + 3, p2.y, p2.z, p2.w);
    }
#undef UPD

    pd[(seg * 3 + 0) * 64 + ql] = d0;   pi[(seg * 3 + 0) * 64 + ql] = i0;
    pd[(seg * 3 + 1) * 64 + ql] = d1v;  pi[(seg * 3 + 1) * 64 + ql] = i1;
    pd[(seg * 3 + 2) * 64 + ql] = d2v;  pi[(seg * 3 + 2) * 64 + ql] = i2;
    __syncthreads();

    if (tid < 64) {
        // merge 12 entries in (segment asc, within-list asc) order
        float e0 = pd[0 * 64 + tid], e1 = pd[1 * 64 + tid], e2 = pd[2 * 64 + tid];
        int   j0 = pi[0 * 64 + tid], j1 = pi[1 * 64 + tid], j2 = pi[2 * 64 + tid];
#pragma unroll
        for (int s = 3; s < 12; s++) {
            float d = pd[s * 64 + tid];
            int   i = pi[s * 64 + tid];
            bool c2 = d < e2;
            e2 = c2 ? d : e2;  j2 = c2 ? i : j2;
            bool c1 = e2 < e1;
            float tf = e1; e1 = c1 ? e2 : e1; e2 = c1 ? tf : e2;
            int   ti = j1; j1 = c1 ? j2 : j1; j2 = c1 ? ti : j2;
            bool c0 = e1 < e0;
            tf = e0; e0 = c0 ? e1 : e0; e1 = c0 ? tf : e1;
            ti = j0; j0 = c0 ? j1 : j0; j1 = c0 ? ti : j1;
        }
        const float eps = 1.1920929e-07f;
        float v0 = 1.0f / __fadd_rn(e0, eps);
        float v1 = 1.0f / __fadd_rn(e1, eps);
        float v2 = 1.0f / __fadd_rn(e2, eps);
        float s  = __fadd_rn(__fadd_rn(v0, v1), v2);
        sidx[tid * 3 + 0] = j0;  swt[tid * 3 + 0] = v0 / s;
        sidx[tid * 3 + 1] = j1;  swt[tid * 3 + 1] = v1 / s;
        sidx[tid * 3 + 2] = j2;  swt[tid * 3 + 2] = v2 / s;
    }
    __syncthreads();

    // ---- interp + concat phase: wave w handles queries w*16..w*16+15 ----
    const int lane = tid & 63, wv = tid >> 6;
    const float* fb = f1 + (size_t)batch * (N1 * D1c);
#pragma unroll 2
    for (int it = 0; it < 16; it++) {
        const int q  = wv * 16 + it;
        const int nr = batch * NP + qblk * 64 + q;
        const int a0 = sidx[q * 3 + 0], a1 = sidx[q * 3 + 1], a2 = sidx[q * 3 + 2];
        const float w0 = swt[q * 3 + 0], w1 = swt[q * 3 + 1], w2 = swt[q * 3 + 2];
        float4 a = *(const float4*)(fb + (size_t)a0 * D1c + lane * 4);
        float4 b = *(const float4*)(fb + (size_t)a1 * D1c + lane * 4);
        float4 c = *(const float4*)(fb + (size_t)a2 * D1c + lane * 4);
        ushort4 o;
        o.x = f2b(__fadd_rn(__fadd_rn(__fmul_rn(a.x,w0), __fmul_rn(b.x,w1)), __fmul_rn(c.x,w2)));
        o.y = f2b(__fadd_rn(__fadd_rn(__fmul_rn(a.y,w0), __fmul_rn(b.y,w1)), __fmul_rn(c.y,w2)));
        o.z = f2b(__fadd_rn(__fadd_rn(__fmul_rn(a.z,w0), __fmul_rn(b.z,w1)), __fmul_rn(c.z,w2)));
        o.w = f2b(__fadd_rn(__fadd_rn(__fmul_rn(a.w,w0), __fmul_rn(b.w,w1)), __fmul_rn(c.w,w2)));
        *(ushort4*)(x + (size_t)nr * KD1 + lane * 4) = o;
        float2 f = *(const float2*)(feat2 + (size_t)nr * D2c + lane * 2);
        ushort2 o2; o2.x = f2b(f.x); o2.y = f2b(f.y);
        *(ushort2*)(x + (size_t)nr * KD1 + D1c + lane * 2) = o2;
    }
}

// ---------------- GEMM (A: M x K, Bw: 256 x K "B^T"), bias + BN-partials fused --
// 512 threads = 8 waves (2 m-halves x 4 n-quarters of 64x64). Full N=256 per
// block -> A read once. Single-barrier double-buffer: stage(ck+1) -> compute(ck)
// -> __syncthreads(). Epilogue: LDS transpose -> contiguous 16 B/lane stores.
// BN partials: P[slot][col], 64 B rows.
template<int KD>
__global__ __launch_bounds__(512, 2) void gemm_bn(
    const unsigned short* __restrict__ A,
    const unsigned short* __restrict__ Bw,
    const float* __restrict__ bias,
    unsigned short* __restrict__ Out,
    float* __restrict__ Psum, float* __restrict__ Psq)
{
    __shared__ short smem[24576];   // 48 KB: As[2] @ 0/4096, Bs[2] @ 8192/16384
    const int tid  = threadIdx.x;
    const int wave = tid >> 6, lane = tid & 63;
    const int wm   = wave & 1, wn = wave >> 1;
    const int quad = lane >> 4, l16 = lane & 15;
    const long m0 = (long)blockIdx.x * 128;

    const int srow = tid >> 2;
    const int cg   = ((tid & 3) ^ ((tid >> 3) & 3)) * 8;
    const size_t aoff  = (size_t)(m0 + srow) * KD + cg;
    const size_t boff0 = (size_t)(srow) * KD + cg;
    const size_t boff1 = (size_t)(128 + srow) * KD + cg;

    floatx4 acc[4][4];
#pragma unroll
    for (int a = 0; a < 4; a++)
#pragma unroll
        for (int b = 0; b < 4; b++)
            acc[a][b] = floatx4{0.f, 0.f, 0.f, 0.f};

    const int rsw = (l16 >> 1) & 3;   // fragment-read swizzle
    constexpr int NK = KD / 32;

#define STAGE(buf, ck) do {                                                         \
        __builtin_amdgcn_global_load_lds((gas_t)(const void*)(A + aoff + (ck)*32),  \
            (las_t)(void*)(smem + (buf)*4096 + wave*512), 16, 0, 0);                \
        __builtin_amdgcn_global_load_lds((gas_t)(const void*)(Bw + boff0 + (ck)*32),\
            (las_t)(void*)(smem + 8192 + (buf)*8192 + wave*512), 16, 0, 0);         \
        __builtin_amdgcn_global_load_lds((gas_t)(const void*)(Bw + boff1 + (ck)*32),\
            (las_t)(void*)(smem + 8192 + (buf)*8192 + 4096 + wave*512), 16, 0, 0);  \
    } while (0)

    STAGE(0, 0);
    __syncthreads();

    for (int ck = 0; ck < NK; ck++) {
        const int cur = ck & 1;
        if (ck + 1 < NK) STAGE(cur ^ 1, ck + 1);

        const short* Ab = smem + cur * 4096;
        const short* Bb = smem + 8192 + cur * 8192;
        short8 af[4], bfr[4];
#pragma unroll
        for (int mb = 0; mb < 4; mb++)
            af[mb] = *(const short8*)(Ab + (wm * 64 + mb * 16 + l16) * 32 + ((quad ^ rsw) * 8));
#pragma unroll
        for (int nb = 0; nb < 4; nb++)
            bfr[nb] = *(const short8*)(Bb + (wn * 64 + nb * 16 + l16) * 32 + ((quad ^ rsw) * 8));
#pragma unroll
        for (int mb = 0; mb < 4; mb++)
#pragma unroll
            for (int nb = 0; nb < 4; nb++)
                acc[mb][nb] = __builtin_amdgcn_mfma_f32_16x16x32_bf16(af[mb], bfr[nb], acc[mb][nb], 0, 0, 0);
        __syncthreads();
    }
#undef STAGE

    // bias + BN partials (P[slot][col]: contiguous 64 B per 16-lane store)
    const int pslot = blockIdx.x * 2 + wm;
#pragma unroll
    for (int nb = 0; nb < 4; nb++) {
        const int col = wn * 64 + nb * 16 + l16;
        const float bia = bias[col];
        float s = 0.f, q = 0.f;
#pragma unroll
        for (int mb = 0; mb < 4; mb++)
#pragma unroll
            for (int r = 0; r < 4; r++) {
                float v = acc[mb][nb][r] + bia;
                acc[mb][nb][r] = v;
                s += v; q += v * v;
            }
        s += __shfl_xor(s, 16); s += __shfl_xor(s, 32);
        q += __shfl_xor(q, 16); q += __shfl_xor(q, 32);
        if (quad == 0) {
            Psum[pslot * 256 + col] = s;
            Psq [pslot * 256 + col] = q;
        }
    }

    // epilogue: 2 passes of 64 rows through LDS (32 KB), contiguous stores.
#pragma unroll
    for (int p = 0; p < 2; p++) {
        __syncthreads();
        if (wm == p) {
#pragma unroll
            for (int mb = 0; mb < 4; mb++)
#pragma unroll
                for (int r = 0; r < 4; r++) {
                    const int rl = mb * 16 + quad * 4 + r;
#pragma unroll
                    for (int nb = 0; nb < 4; nb++) {
                        const int col = wn * 64 + nb * 16 + l16;
                        smem[rl * 256 + ((((col >> 3) + rl) & 31) << 3) + (col & 7)] =
                            (short)f2b(acc[mb][nb][r]);
                    }
                }
        }
        __syncthreads();
#pragma unroll
        for (int rr = 0; rr < 4; rr++) {
            const int rl = rr * 16 + (tid >> 5);
            const int c  = tid & 31;
            short8 v = *(const short8*)(smem + rl * 256 + (((c + rl) & 31) << 3));
            *(short8*)(Out + (size_t)(m0 + p * 64 + rl) * 256 + c * 8) = v;
        }
    }
}

// ---------------- BN finalize: reduce P[1024][256] -> scale/shift --------
__global__ __launch_bounds__(256) void finalize_bn(
    const float* __restrict__ Psum, const float* __restrict__ Psq,
    const float* __restrict__ g, const float* __restrict__ beta,
    float* __restrict__ scale, float* __restrict__ shift)
{
    __shared__ float ls[8][32], lq[8][32];
    const int cl = threadIdx.x & 31, grp = threadIdx.x >> 5;
    const int c = blockIdx.x * 32 + cl;
    float s = 0.f, q = 0.f;
    for (int k = grp * 128; k < grp * 128 + 128; k++) {
        s += Psum[k * 256 + c];
        q += Psq [k * 256 + c];
    }
    ls[grp][cl] = s; lq[grp][cl] = q;
    __syncthreads();
    if (grp == 0) {
#pragma unroll
        for (int k = 1; k < 8; k++) { s += ls[k][cl]; q += lq[k][cl]; }
        float m  = s * (1.0f / (float)NQ);
        float v  = q * (1.0f / (float)NQ) - m * m;
        float rs = rsqrtf(v + 1e-5f);
        float a  = rs * g[c];
        scale[c] = a;
        shift[c] = fmaf(-m, a, beta[c]);
    }
}

// ---------------- BN apply + relu: y1 bf16 -> x2 bf16 ----------------
__global__ __launch_bounds__(256) void bn_apply(
    const unsigned short* __restrict__ y1, const float* __restrict__ scale,
    const float* __restrict__ shift, unsigned short* __restrict__ x2)
{
    size_t t = (size_t)blockIdx.x * 256 + threadIdx.x;   // 2,097,152 threads x 8 elems
    int c = ((int)t & 31) * 8;
    const ushort4* in = (const ushort4*)y1 + t * 2;
    ushort4 a = in[0], b = in[1];
    float4 s0 = *(const float4*)(scale + c), s1 = *(const float4*)(scale + c + 4);
    float4 h0 = *(const float4*)(shift + c), h1 = *(const float4*)(shift + c + 4);
    ushort4 oa, ob;
    oa.x = f2b(fmaxf(fmaf(b2f(a.x), s0.x, h0.x), 0.f));
    oa.y = f2b(fmaxf(fmaf(b2f(a.y), s0.y, h0.y), 0.f));
    oa.z = f2b(fmaxf(fmaf(b2f(a.z), s0.z, h0.z), 0.f));
    oa.w = f2b(fmaxf(fmaf(b2f(a.w), s0.w, h0.w), 0.f));
    ob.x = f2b(fmaxf(fmaf(b2f(b.x), s1.x, h1.x), 0.f));
    ob.y = f2b(fmaxf(fmaf(b2f(b.y), s1.y, h1.y), 0.f));
    ob.z = f2b(fmaxf(fmaf(b2f(b.z), s1.z, h1.z), 0.f));
    ob.w = f2b(fmaxf(fmaf(b2f(b.w), s1.w, h1.w), 0.f));
    ushort4* op = (ushort4*)x2 + t * 2;
    op[0] = oa; op[1] = ob;
}

// ---------------- final BN apply + relu: y2 bf16 -> d_out fp32 ----------------
__global__ __launch_bounds__(256) void final_apply(
    const unsigned short* __restrict__ y2, const float* __restrict__ scale,
    const float* __restrict__ shift, float* __restrict__ out)
{
    size_t t = (size_t)blockIdx.x * 256 + threadIdx.x;   // 2,097,152 threads x 8 elems
    int c = ((int)t & 31) * 8;
    const ushort4* in = (const ushort4*)y2 + t * 2;
    ushort4 a = in[0], b = in[1];
    float4 s0 = *(const float4*)(scale + c), s1 = *(const float4*)(scale + c + 4);
    float4 h0 = *(const float4*)(shift + c), h1 = *(const float4*)(shift + c + 4);
    float4 o0, o1;
    o0.x = fmaxf(fmaf(b2f(a.x), s0.x, h0.x), 0.f);
    o0.y = fmaxf(fmaf(b2f(a.y), s0.y, h0.y), 0.f);
    o0.z = fmaxf(fmaf(b2f(a.z), s0.z, h0.z), 0.f);
    o0.w = fmaxf(fmaf(b2f(a.w), s0.w, h0.w), 0.f);
    o1.x = fmaxf(fmaf(b2f(b.x), s1.x, h1.x), 0.f);
    o1.y = fmaxf(fmaf(b2f(b.y), s1.y, h1.y), 0.f);
    o1.z = fmaxf(fmaf(b2f(b.z), s1.z, h1.z), 0.f);
    o1.w = fmaxf(fmaf(b2f(b.w), s1.w, h1.w), 0.f);
    ((float4*)out)[t * 2]     = o0;
    ((float4*)out)[t * 2 + 1] = o1;
}

extern "C" void kernel_launch(void* const* d_in, const int* in_sizes, int n_in,
                              void* d_out, int out_size, void* d_ws, size_t ws_size,
                              hipStream_t stream) {
    (void)in_sizes; (void)n_in; (void)out_size; (void)ws_size;
    const float* xyz1 = (const float*)d_in[0];
    const float* xyz2 = (const float*)d_in[1];
    const float* f1   = (const float*)d_in[2];
    const float* f2   = (const float*)d_in[3];
    const float* W1   = (const float*)d_in[4];
    const float* b1   = (const float*)d_in[5];
    const float* g1   = (const float*)d_in[6];
    const float* be1  = (const float*)d_in[7];
    const float* W2   = (const float*)d_in[8];
    const float* b2   = (const float*)d_in[9];
    const float* g2   = (const float*)d_in[10];
    const float* be2  = (const float*)d_in[11];

    char* ws = (char*)d_ws;
    unsigned short* X    = (unsigned short*)(ws + X_OFF);     // x, later reused as x2
    unsigned short* Y1   = (unsigned short*)(ws + Y1_OFF);    // y1, later reused as y2
    float*          SC1  = (float*)(ws + SCALE1_OFF);
    float*          SH1  = (float*)(ws + SHIFT1_OFF);
    float*          SC2  = (float*)(ws + SCALE2_OFF);
    float*          SH2  = (float*)(ws + SHIFT2_OFF);
    unsigned short* W1b  = (unsigned short*)(ws + W1B_OFF);
    unsigned short* W2b  = (unsigned short*)(ws + W2B_OFF);
    float*          PS   = (float*)(ws + PS_OFF);
    float*          PQ   = (float*)(ws + PQ_OFF);

    knn_interp_kernel<<<1664, 256, 0, stream>>>(xyz1, xyz2, f1, f2, W1, W2, W1b, W2b, X);
    gemm_bn<KD1><<<512, 512, 0, stream>>>(X, W1b, b1, Y1, PS, PQ);
    finalize_bn<<<8, 256, 0, stream>>>(PS, PQ, g1, be1, SC1, SH1);
    bn_apply<<<(NQ * DH) / (8 * 256), 256, 0, stream>>>(Y1, SC1, SH1, X);
    gemm_bn<DH><<<512, 512, 0, stream>>>(X, W2b, b2, Y1, PS, PQ);
    finalize_bn<<<8, 256, 0, stream>>>(PS, PQ, g2, be2, SC2, SH2);
    final_apply<<<(NQ * DH) / (8 * 256), 256, 0, stream>>>(Y1, SC2, SH2, (float*)d_out);
}

// Round 7
// 260.239 us; speedup vs baseline: 1.1801x; 1.0064x over previous
//
#include <hip/hip_runtime.h>
#include <hip/hip_bf16.h>

// Problem constants (fixed by setup_inputs)
#define B_    16
#define N1    1024
#define NP    4096
#define D1c   256
#define D2c   128
#define DH    256
#define NQ    (B_*NP)        // 65536 rows
#define KD1   (D1c+D2c)      // 384

// Workspace layout (bytes).
#define X_OFF      0ul                     // x / x2 bf16: 65536*384*2
#define Y1_OFF     50331648ul              // y1 / y2 bf16: 65536*256*2
#define SCALE1_OFF 85458944ul
#define SHIFT1_OFF (SCALE1_OFF+1024ul)
#define SCALE2_OFF (SCALE1_OFF+2048ul)
#define SHIFT2_OFF (SCALE1_OFF+3072ul)
#define W1B_OFF    85467136ul              // bf16 W1: 256*384*2
#define W2B_OFF    85663744ul              // bf16 W2: 256*256*2
#define PS_OFF     85794816ul              // float Psum[1024][256] = 1 MB
#define PQ_OFF     86843392ul              // float Psq [1024][256] = 1 MB

using short8  = __attribute__((ext_vector_type(8))) short;
using floatx4 = __attribute__((ext_vector_type(4))) float;
using f4v     = __attribute__((ext_vector_type(4))) float;
using f2v     = __attribute__((ext_vector_type(2))) float;
typedef const __attribute__((address_space(1))) unsigned int* gas_t;
typedef __attribute__((address_space(3))) unsigned int* las_t;
typedef const __attribute__((address_space(4))) float* c4f_t;   // constant AS -> s_load
typedef const __attribute__((address_space(4))) f4v*   c4v_t;

// bf16 RNE cast (bit-level, matches np/jax round-to-nearest-even; inputs finite)
static __device__ __forceinline__ unsigned short f2b(float f) {
    unsigned int u = __builtin_bit_cast(unsigned int, f);
    return (unsigned short)((u + 0x7FFFu + ((u >> 16) & 1u)) >> 16);
}
static __device__ __forceinline__ float b2f(unsigned short u) {
    unsigned int x = ((unsigned int)u) << 16;
    return __builtin_bit_cast(float, x);
}

// ---------------- fused kNN + interp/concat (+ weight cvt on spare blocks) ----
// Blocks 0..1023: 64 queries each, remapped so each XCD (blockIdx&7) owns 2
// batches -> f1 gather working set (2 MB) fits per-XCD L2. Phase 1: kNN k=3,
// candidates via constant-AS scalar loads; distances packed 2-per-float2 under
// fp contract(off) (bit-exact IEEE RNE, numpy order ((dx*dx+dy*dy)+dz*dz)).
// Selection: values min/med3, indices cmp+cndmask -- verified equal to strict-<
// insertion incl. bit-equal ties. Phase 2: 12-way merge (segment asc order,
// first-occurrence top_k semantics). Phase 3: interp+concat 64 rows -> x bf16.
// Blocks 1024..1663: W1/W2 fp32->bf16 conversion.
__global__ __launch_bounds__(256) void knn_interp_kernel(
    const float* __restrict__ xyz1, const float* __restrict__ xyz2,
    const float* __restrict__ f1,   const float* __restrict__ feat2,
    const float* __restrict__ W1,   const float* __restrict__ W2,
    unsigned short* __restrict__ W1b, unsigned short* __restrict__ W2b,
    unsigned short* __restrict__ x)
{
#pragma clang fp contract(off)
    const int tid = threadIdx.x;
    if (blockIdx.x >= 1024) {            // ---- weight conversion blocks ----
        int i = (blockIdx.x - 1024) * 256 + tid;
        if (i < DH * KD1) W1b[i] = f2b(W1[i]);
        else              W2b[i - DH * KD1] = f2b(W2[i - DH * KD1]);
        return;
    }

    __shared__ float pd[12 * 64];     // partial dists  [(seg*3+k)*64 + ql]
    __shared__ int   pi[12 * 64];     // partial indices
    __shared__ int   sidx[64 * 3];
    __shared__ float swt [64 * 3];

    // XCD-affinity remap: xcd = blockIdx&7 owns batches {2*xcd, 2*xcd+1}
    const int xcd  = blockIdx.x & 7;
    const int slot = blockIdx.x >> 3;          // 0..127
    const int batch = xcd * 2 + (slot >> 6);
    const int qblk  = slot & 63;

    const int ql  = tid & 63;                 // query lane within block
    const int seg = tid >> 6;                 // candidate segment 0..3
    const int seg_u = __builtin_amdgcn_readfirstlane(seg);   // wave-uniform
    const int n = batch * NP + qblk * 64 + ql;
    const float* qp = xyz2 + (size_t)n * 3;
    const float qx = qp[0], qy = qp[1], qz = qp[2];
    const f2v qx2 = {qx, qx}, qy2 = {qy, qy}, qz2 = {qz, qz};

    // candidate pointer: constant-AS, uniform -> scalar loads (48 B / 4 cands)
    c4f_t cp = (c4f_t)(const void*)(xyz1 + (size_t)batch * (N1 * 3))
               + (size_t)seg_u * 768;

    float d0 = 3.4e38f, d1v = 3.4e38f, d2v = 3.4e38f;
    int   i0 = 0, i1 = 0, i2 = 0;

    // selection: values via min/med3, indices via cmp+cndmask.
    // Verified identical (incl. bit-equal ties) to strict-< sorted insertion.
#define SEL(jj, dd) do {                                                      \
        bool c0 = (dd) < d0, c1 = (dd) < d1v, c2 = (dd) < d2v;                \
        i2 = c2 ? (c1 ? i1 : (jj)) : i2;                                      \
        i1 = c1 ? (c0 ? i0 : (jj)) : i1;                                      \
        i0 = c0 ? (jj) : i0;                                                  \
        d2v = __builtin_amdgcn_fmed3f(d1v, d2v, (dd));                        \
        d1v = __builtin_amdgcn_fmed3f(d0, d1v, (dd));                         \
        d0  = fminf(d0, (dd));                                                \
    } while (0)

    const int jbase = seg_u * 256;
    for (int j = 0; j < 256; j += 4) {
        f4v p0 = *(c4v_t)(cp + j * 3);
        f4v p1 = *(c4v_t)(cp + j * 3 + 4);
        f4v p2 = *(c4v_t)(cp + j * 3 + 8);
        // pair (j, j+1)
        {
            f2v cx2 = {p0.x, p0.w}, cy2 = {p0.y, p1.x}, cz2 = {p0.z, p1.y};
            f2v dx2 = qx2 - cx2, dy2 = qy2 - cy2, dz2 = qz2 - cz2;
            f2v dd2 = (dx2 * dx2 + dy2 * dy2) + dz2 * dz2;
            SEL(jbase + j + 0, dd2.x);
            SEL(jbase + j + 1, dd2.y);
        }
        // pair (j+2, j+3)
        {
            f2v cx2 = {p1.z, p2.y}, cy2 = {p1.w, p2.z}, cz2 = {p2.x, p2.w};
            f2v dx2 = qx2 - cx2, dy2 = qy2 - cy2, dz2 = qz2 - cz2;
            f2v dd2 = (dx2 * dx2 + dy2 * dy2) + dz2 * dz2;
            SEL(jbase + j + 2, dd2.x);
            SEL(jbase + j + 3, dd2.y);
        }
    }
#undef SEL

    pd[(seg * 3 + 0) * 64 + ql] = d0;   pi[(seg * 3 + 0) * 64 + ql] = i0;
    pd[(seg * 3 + 1) * 64 + ql] = d1v;  pi[(seg * 3 + 1) * 64 + ql] = i1;
    pd[(seg * 3 + 2) * 64 + ql] = d2v;  pi[(seg * 3 + 2) * 64 + ql] = i2;
    __syncthreads();

    if (tid < 64) {
        // merge 12 entries in (segment asc, within-list asc) order
        float e0 = pd[0 * 64 + tid], e1 = pd[1 * 64 + tid], e2 = pd[2 * 64 + tid];
        int   j0 = pi[0 * 64 + tid], j1 = pi[1 * 64 + tid], j2 = pi[2 * 64 + tid];
#pragma unroll
        for (int s = 3; s < 12; s++) {
            float d = pd[s * 64 + tid];
            int   i = pi[s * 64 + tid];
            bool c2 = d < e2;
            e2 = c2 ? d : e2;  j2 = c2 ? i : j2;
            bool c1 = e2 < e1;
            float tf = e1; e1 = c1 ? e2 : e1; e2 = c1 ? tf : e2;
            int   ti = j1; j1 = c1 ? j2 : j1; j2 = c1 ? ti : j2;
            bool c0 = e1 < e0;
            tf = e0; e0 = c0 ? e1 : e0; e1 = c0 ? tf : e1;
            ti = j0; j0 = c0 ? j1 : j0; j1 = c0 ? ti : j1;
        }
        const float eps = 1.1920929e-07f;
        float v0 = 1.0f / __fadd_rn(e0, eps);
        float v1 = 1.0f / __fadd_rn(e1, eps);
        float v2 = 1.0f / __fadd_rn(e2, eps);
        float s  = __fadd_rn(__fadd_rn(v0, v1), v2);
        sidx[tid * 3 + 0] = j0;  swt[tid * 3 + 0] = v0 / s;
        sidx[tid * 3 + 1] = j1;  swt[tid * 3 + 1] = v1 / s;
        sidx[tid * 3 + 2] = j2;  swt[tid * 3 + 2] = v2 / s;
    }
    __syncthreads();

    // ---- interp + concat phase: wave w handles queries w*16..w*16+15 ----
    const int lane = tid & 63, wv = tid >> 6;
    const float* fb = f1 + (size_t)batch * (N1 * D1c);
#pragma unroll 4
    for (int it = 0; it < 16; it++) {
        const int q  = wv * 16 + it;
        const int nr = batch * NP + qblk * 64 + q;
        const int a0 = sidx[q * 3 + 0], a1 = sidx[q * 3 + 1], a2 = sidx[q * 3 + 2];
        const float w0 = swt[q * 3 + 0], w1 = swt[q * 3 + 1], w2 = swt[q * 3 + 2];
        float4 a = *(const float4*)(fb + (size_t)a0 * D1c + lane * 4);
        float4 b = *(const float4*)(fb + (size_t)a1 * D1c + lane * 4);
        float4 c = *(const float4*)(fb + (size_t)a2 * D1c + lane * 4);
        ushort4 o;
        o.x = f2b(__fadd_rn(__fadd_rn(__fmul_rn(a.x,w0), __fmul_rn(b.x,w1)), __fmul_rn(c.x,w2)));
        o.y = f2b(__fadd_rn(__fadd_rn(__fmul_rn(a.y,w0), __fmul_rn(b.y,w1)), __fmul_rn(c.y,w2)));
        o.z = f2b(__fadd_rn(__fadd_rn(__fmul_rn(a.z,w0), __fmul_rn(b.z,w1)), __fmul_rn(c.z,w2)));
        o.w = f2b(__fadd_rn(__fadd_rn(__fmul_rn(a.w,w0), __fmul_rn(b.w,w1)), __fmul_rn(c.w,w2)));
        *(ushort4*)(x + (size_t)nr * KD1 + lane * 4) = o;
        float2 f = *(const float2*)(feat2 + (size_t)nr * D2c + lane * 2);
        ushort2 o2; o2.x = f2b(f.x); o2.y = f2b(f.y);
        *(ushort2*)(x + (size_t)nr * KD1 + D1c + lane * 2) = o2;
    }
}

// ---------------- GEMM (A: M x K, Bw: 256 x K "B^T"), bias + BN-partials fused --
// 512 threads = 8 waves (2 m-halves x 4 n-quarters of 64x64). Full N=256 per
// block -> A read once. Single-barrier double-buffer: stage(ck+1) -> compute(ck)
// -> __syncthreads(). Epilogue: LDS transpose -> contiguous 16 B/lane stores.
// BN partials: P[slot][col], 64 B rows.
template<int KD>
__global__ __launch_bounds__(512, 2) void gemm_bn(
    const unsigned short* __restrict__ A,
    const unsigned short* __restrict__ Bw,
    const float* __restrict__ bias,
    unsigned short* __restrict__ Out,
    float* __restrict__ Psum, float* __restrict__ Psq)
{
    __shared__ short smem[24576];   // 48 KB: As[2] @ 0/4096, Bs[2] @ 8192/16384
    const int tid  = threadIdx.x;
    const int wave = tid >> 6, lane = tid & 63;
    const int wm   = wave & 1, wn = wave >> 1;
    const int quad = lane >> 4, l16 = lane & 15;
    const long m0 = (long)blockIdx.x * 128;

    const int srow = tid >> 2;
    const int cg   = ((tid & 3) ^ ((tid >> 3) & 3)) * 8;
    const size_t aoff  = (size_t)(m0 + srow) * KD + cg;
    const size_t boff0 = (size_t)(srow) * KD + cg;
    const size_t boff1 = (size_t)(128 + srow) * KD + cg;

    floatx4 acc[4][4];
#pragma unroll
    for (int a = 0; a < 4; a++)
#pragma unroll
        for (int b = 0; b < 4; b++)
            acc[a][b] = floatx4{0.f, 0.f, 0.f, 0.f};

    const int rsw = (l16 >> 1) & 3;   // fragment-read swizzle
    constexpr int NK = KD / 32;

#define STAGE(buf, ck) do {                                                         \
        __builtin_amdgcn_global_load_lds((gas_t)(const void*)(A + aoff + (ck)*32),  \
            (las_t)(void*)(smem + (buf)*4096 + wave*512), 16, 0, 0);                \
        __builtin_amdgcn_global_load_lds((gas_t)(const void*)(Bw + boff0 + (ck)*32),\
            (las_t)(void*)(smem + 8192 + (buf)*8192 + wave*512), 16, 0, 0);         \
        __builtin_amdgcn_global_load_lds((gas_t)(const void*)(Bw + boff1 + (ck)*32),\
            (las_t)(void*)(smem + 8192 + (buf)*8192 + 4096 + wave*512), 16, 0, 0);  \
    } while (0)

    STAGE(0, 0);
    __syncthreads();

    for (int ck = 0; ck < NK; ck++) {
        const int cur = ck & 1;
        if (ck + 1 < NK) STAGE(cur ^ 1, ck + 1);

        const short* Ab = smem + cur * 4096;
        const short* Bb = smem + 8192 + cur * 8192;
        short8 af[4], bfr[4];
#pragma unroll
        for (int mb = 0; mb < 4; mb++)
            af[mb] = *(const short8*)(Ab + (wm * 64 + mb * 16 + l16) * 32 + ((quad ^ rsw) * 8));
#pragma unroll
        for (int nb = 0; nb < 4; nb++)
            bfr[nb] = *(const short8*)(Bb + (wn * 64 + nb * 16 + l16) * 32 + ((quad ^ rsw) * 8));
#pragma unroll
        for (int mb = 0; mb < 4; mb++)
#pragma unroll
            for (int nb = 0; nb < 4; nb++)
                acc[mb][nb] = __builtin_amdgcn_mfma_f32_16x16x32_bf16(af[mb], bfr[nb], acc[mb][nb], 0, 0, 0);
        __syncthreads();
    }
#undef STAGE

    // bias + BN partials (P[slot][col]: contiguous 64 B per 16-lane store)
    const int pslot = blockIdx.x * 2 + wm;
#pragma unroll
    for (int nb = 0; nb < 4; nb++) {
        const int col = wn * 64 + nb * 16 + l16;
        const float bia = bias[col];
        float s = 0.f, q = 0.f;
#pragma unroll
        for (int mb = 0; mb < 4; mb++)
#pragma unroll
            for (int r = 0; r < 4; r++) {
                float v = acc[mb][nb][r] + bia;
                acc[mb][nb][r] = v;
                s += v; q += v * v;
            }
        s += __shfl_xor(s, 16); s += __shfl_xor(s, 32);
        q += __shfl_xor(q, 16); q += __shfl_xor(q, 32);
        if (quad == 0) {
            Psum[pslot * 256 + col] = s;
            Psq [pslot * 256 + col] = q;
        }
    }

    // epilogue: 2 passes of 64 rows through LDS (32 KB), contiguous stores.
#pragma unroll
    for (int p = 0; p < 2; p++) {
        __syncthreads();
        if (wm == p) {
#pragma unroll
            for (int mb = 0; mb < 4; mb++)
#pragma unroll
                for (int r = 0; r < 4; r++) {
                    const int rl = mb * 16 + quad * 4 + r;
#pragma unroll
                    for (int nb = 0; nb < 4; nb++) {
                        const int col = wn * 64 + nb * 16 + l16;
                        smem[rl * 256 + ((((col >> 3) + rl) & 31) << 3) + (col & 7)] =
                            (short)f2b(acc[mb][nb][r]);
                    }
                }
        }
        __syncthreads();
#pragma unroll
        for (int rr = 0; rr < 4; rr++) {
            const int rl = rr * 16 + (tid >> 5);
            const int c  = tid & 31;
            short8 v = *(const short8*)(smem + rl * 256 + (((c + rl) & 31) << 3));
            *(short8*)(Out + (size_t)(m0 + p * 64 + rl) * 256 + c * 8) = v;
        }
    }
}

// ---------------- BN finalize: reduce P[1024][256] -> scale/shift --------
__global__ __launch_bounds__(256) void finalize_bn(
    const float* __restrict__ Psum, const float* __restrict__ Psq,
    const float* __restrict__ g, const float* __restrict__ beta,
    float* __restrict__ scale, float* __restrict__ shift)
{
    __shared__ float ls[8][32], lq[8][32];
    const int cl = threadIdx.x & 31, grp = threadIdx.x >> 5;
    const int c = blockIdx.x * 32 + cl;
    float s = 0.f, q = 0.f;
    for (int k = grp * 128; k < grp * 128 + 128; k++) {
        s += Psum[k * 256 + c];
        q += Psq [k * 256 + c];
    }
    ls[grp][cl] = s; lq[grp][cl] = q;
    __syncthreads();
    if (grp == 0) {
#pragma unroll
        for (int k = 1; k < 8; k++) { s += ls[k][cl]; q += lq[k][cl]; }
        float m  = s * (1.0f / (float)NQ);
        float v  = q * (1.0f / (float)NQ) - m * m;
        float rs = rsqrtf(v + 1e-5f);
        float a  = rs * g[c];
        scale[c] = a;
        shift[c] = fmaf(-m, a, beta[c]);
    }
}

// ---------------- BN apply + relu: y1 bf16 -> x2 bf16 ----------------
__global__ __launch_bounds__(256) void bn_apply(
    const unsigned short* __restrict__ y1, const float* __restrict__ scale,
    const float* __restrict__ shift, unsigned short* __restrict__ x2)
{
    size_t t = (size_t)blockIdx.x * 256 + threadIdx.x;   // 2,097,152 threads x 8 elems
    int c = ((int)t & 31) * 8;
    const ushort4* in = (const ushort4*)y1 + t * 2;
    ushort4 a = in[0], b = in[1];
    float4 s0 = *(const float4*)(scale + c), s1 = *(const float4*)(scale + c + 4);
    float4 h0 = *(const float4*)(shift + c), h1 = *(const float4*)(shift + c + 4);
    ushort4 oa, ob;
    oa.x = f2b(fmaxf(fmaf(b2f(a.x), s0.x, h0.x), 0.f));
    oa.y = f2b(fmaxf(fmaf(b2f(a.y), s0.y, h0.y), 0.f));
    oa.z = f2b(fmaxf(fmaf(b2f(a.z), s0.z, h0.z), 0.f));
    oa.w = f2b(fmaxf(fmaf(b2f(a.w), s0.w, h0.w), 0.f));
    ob.x = f2b(fmaxf(fmaf(b2f(b.x), s1.x, h1.x), 0.f));
    ob.y = f2b(fmaxf(fmaf(b2f(b.y), s1.y, h1.y), 0.f));
    ob.z = f2b(fmaxf(fmaf(b2f(b.z), s1.z, h1.z), 0.f));
    ob.w = f2b(fmaxf(fmaf(b2f(b.w), s1.w, h1.w), 0.f));
    ushort4* op = (ushort4*)x2 + t * 2;
    op[0] = oa; op[1] = ob;
}

// ---------------- final BN apply + relu: y2 bf16 -> d_out fp32 ----------------
__global__ __launch_bounds__(256) void final_apply(
    const unsigned short* __restrict__ y2, const float* __restrict__ scale,
    const float* __restrict__ shift, float* __restrict__ out)
{
    size_t t = (size_t)blockIdx.x * 256 + threadIdx.x;   // 2,097,152 threads x 8 elems
    int c = ((int)t & 31) * 8;
    const ushort4* in = (const ushort4*)y2 + t * 2;
    ushort4 a = in[0], b = in[1];
    float4 s0 = *(const float4*)(scale + c), s1 = *(const float4*)(scale + c + 4);
    float4 h0 = *(const float4*)(shift + c), h1 = *(const float4*)(shift + c + 4);
    float4 o0, o1;
    o0.x = fmaxf(fmaf(b2f(a.x), s0.x, h0.x), 0.f);
    o0.y = fmaxf(fmaf(b2f(a.y), s0.y, h0.y), 0.f);
    o0.z = fmaxf(fmaf(b2f(a.z), s0.z, h0.z), 0.f);
    o0.w = fmaxf(fmaf(b2f(a.w), s0.w, h0.w), 0.f);
    o1.x = fmaxf(fmaf(b2f(b.x), s1.x, h1.x), 0.f);
    o1.y = fmaxf(fmaf(b2f(b.y), s1.y, h1.y), 0.f);
    o1.z = fmaxf(fmaf(b2f(b.z), s1.z, h1.z), 0.f);
    o1.w = fmaxf(fmaf(b2f(b.w), s1.w, h1.w), 0.f);
    ((float4*)out)[t * 2]     = o0;
    ((float4*)out)[t * 2 + 1] = o1;
}

extern "C" void kernel_launch(void* const* d_in, const int* in_sizes, int n_in,
                              void* d_out, int out_size, void* d_ws, size_t ws_size,
                              hipStream_t stream) {
    (void)in_sizes; (void)n_in; (void)out_size; (void)ws_size;
    const float* xyz1 = (const float*)d_in[0];
    const float* xyz2 = (const float*)d_in[1];
    const float* f1   = (const float*)d_in[2];
    const float* f2   = (const float*)d_in[3];
    const float* W1   = (const float*)d_in[4];
    const float* b1   = (const float*)d_in[5];
    const float* g1   = (const float*)d_in[6];
    const float* be1  = (const float*)d_in[7];
    const float* W2   = (const float*)d_in[8];
    const float* b2   = (const float*)d_in[9];
    const float* g2   = (const float*)d_in[10];
    const float* be2  = (const float*)d_in[11];

    char* ws = (char*)d_ws;
    unsigned short* X    = (unsigned short*)(ws + X_OFF);     // x, later reused as x2
    unsigned short* Y1   = (unsigned short*)(ws + Y1_OFF);    // y1, later reused as y2
    float*          SC1  = (float*)(ws + SCALE1_OFF);
    float*          SH1  = (float*)(ws + SHIFT1_OFF);
    float*          SC2  = (float*)(ws + SCALE2_OFF);
    float*          SH2  = (float*)(ws + SHIFT2_OFF);
    unsigned short* W1b  = (unsigned short*)(ws + W1B_OFF);
    unsigned short* W2b  = (unsigned short*)(ws + W2B_OFF);
    float*          PS   = (float*)(ws + PS_OFF);
    float*          PQ   = (float*)(ws + PQ_OFF);

    knn_interp_kernel<<<1664, 256, 0, stream>>>(xyz1, xyz2, f1, f2, W1, W2, W1b, W2b, X);
    gemm_bn<KD1><<<512, 512, 0, stream>>>(X, W1b, b1, Y1, PS, PQ);
    finalize_bn<<<8, 256, 0, stream>>>(PS, PQ, g1, be1, SC1, SH1);
    bn_apply<<<(NQ * DH) / (8 * 256), 256, 0, stream>>>(Y1, SC1, SH1, X);
    gemm_bn<DH><<<512, 512, 0, stream>>>(X, W2b, b2, Y1, PS, PQ);
    finalize_bn<<<8, 256, 0, stream>>>(PS, PQ, g2, be2, SC2, SH2);
    final_apply<<<(NQ * DH) / (8 * 256), 256, 0, stream>>>(Y1, SC2, SH2, (float*)d_out);
}